// Round 10
// baseline (555.573 us; speedup 1.0000x reference)
//
#include <hip/hip_runtime.h>
#include <hip/hip_bf16.h>

#define N_NODES 16000
#define N_EDGES 256000

// ---- workspace layout (4-byte units) — total 830852 * 4B = 3.32 MB (r8-validated) ----
#define OFF_SD     0          // int2  256000  (src,dst) per CSR slot, sorted by dst
#define OFF_SIMB   512000     // float 256000  raw sim -> normalized a (in place)
#define OFF_CNT    768000     // int   16000   per-dst degree
#define OFF_START  784000     // int   16001   CSR row offsets
#define OFF_CUR    800001     // int   16000   fill cursors
#define OFF_WK     816004     // float 5120:  [0,512) W1K*inv32 | [512,5120) W2K^T scaled
#define OFF_WV     821124     // float 9728:  [0,512) W1V*inv32 | [512,9728) W2V^T scaled

#define C_SS 0.027950849718747374f   // (1/sqrt16)*(1/sqrt80)
#define C_SV 0.02282177322938192f    // (1/sqrt8)*(1/(sqrt80*sqrt3))

__device__ __forceinline__ float dot16(const float* h, const float* w) {
  float r = 0.f;
#pragma unroll
  for (int t = 0; t < 16; ++t) r = fmaf(h[t], w[t], r);
  return r;
}

// load a 40-float row (rows are 160B = 16B-aligned) via 10 x float4
__device__ __forceinline__ void load_row40(const float* __restrict__ p, float* xr) {
  const float4* rp = reinterpret_cast<const float4*>(p);
#pragma unroll
  for (int q = 0; q < 10; ++q) {
    float4 f = rp[q];
    xr[4 * q + 0] = f.x; xr[4 * q + 1] = f.y; xr[4 * q + 2] = f.z; xr[4 * q + 3] = f.w;
  }
}

struct EdgeGeom { float vhx, vhy, vhz, y1x, y1y, y1z; };

// geometry + radial basis + h = silu(rad @ W1n); W1 [b*16+t], pre-scaled by 1/sqrt(32)
__device__ __forceinline__ void edge_h(const float* __restrict__ pos, int s, int d,
                                       const float* W1, float* h, EdgeGeom& g) {
  float vx = pos[3 * d + 0] - pos[3 * s + 0];
  float vy = pos[3 * d + 1] - pos[3 * s + 1];
  float vz = pos[3 * d + 2] - pos[3 * s + 2];
  float dist = sqrtf(fmaf(vx, vx, fmaf(vy, vy, vz * vz)));
  float dsafe = fmaxf(dist, 1e-6f);
  float rinv = 1.0f / dsafe;
  g.vhx = vx * rinv; g.vhy = vy * rinv; g.vhz = vz * rinv;
  g.y1x = 1.7320508075688772f * g.vhx;
  g.y1y = 1.7320508075688772f * g.vhy;
  g.y1z = 1.7320508075688772f * g.vhz;
  float pre[16];
#pragma unroll
  for (int t = 0; t < 16; ++t) pre[t] = 0.f;
  float sx, cx;
  sincosf(1.2566370614359172f * dsafe, &sx, &cx);   // pi/R_CUT * dsafe
  cx = fminf(1.f, fmaxf(-1.f, cx));
  float twoc = 2.f * cx;
  float sprev = 0.f, scur = sx;
  float rscale = (dist < 2.5f) ? (5.059644256269407f * rinv) : 0.f;  // sqrt(2/2.5)*sqrt(32)
#pragma unroll
  for (int b = 0; b < 32; ++b) {
    float radb = rscale * scur;
#pragma unroll
    for (int t = 0; t < 16; ++t) pre[t] = fmaf(radb, W1[16 * b + t], pre[t]);
    float snext = fmaf(twoc, scur, -sprev);
    sprev = scur; scur = snext;
  }
#pragma unroll
  for (int t = 0; t < 16; ++t) h[t] = pre[t] / (1.f + __expf(-pre[t]));  // silu
}

// ================= weight prep: scaled+transposed global copies (scalar-path source) ==========
__global__ void k_prep(const float* __restrict__ Wk1, const float* __restrict__ Wk2,
                       const float* __restrict__ Wv1, const float* __restrict__ Wv2,
                       float* __restrict__ WK, float* __restrict__ WV) {
  int tid = blockIdx.x * 256 + threadIdx.x;
  int nt = gridDim.x * 256;
  for (int i = tid; i < 512; i += nt) WK[i] = Wk1[i] * 0.17677669529663687f;
  for (int i = tid; i < 4608; i += nt) {
    int col = i >> 4, t = i & 15;
    WK[512 + i] = Wk2[t * 288 + col] * 0.051031036307982884f;
  }
  for (int i = tid; i < 512; i += nt) WV[i] = Wv1[i] * 0.17677669529663687f;
  for (int i = tid; i < 9216; i += nt) {
    int col = i >> 4, t = i & 15;
    WV[512 + i] = Wv2[t * 576 + col] * 0.051031036307982884f;
  }
}

// ================= CSR build =================
__global__ void k_hist(const int* __restrict__ edst, int* __restrict__ cnt) {
  int e = blockIdx.x * 256 + threadIdx.x;
  atomicAdd(&cnt[edst[e]], 1);
}

__global__ void __launch_bounds__(1024) k_scan(const int* __restrict__ cnt,
                                               int* __restrict__ start, int* __restrict__ cur) {
  __shared__ int part[1024];
  int t = threadIdx.x;
  int base = t * 16;
  int local[16];
  int sum = 0;
#pragma unroll
  for (int i = 0; i < 16; ++i) {
    int idx = base + i;
    int c = (idx < N_NODES) ? cnt[idx] : 0;
    local[i] = sum; sum += c;
  }
  part[t] = sum;
  __syncthreads();
  for (int off = 1; off < 1024; off <<= 1) {
    int v = (t >= off) ? part[t - off] : 0;
    __syncthreads();
    part[t] += v;
    __syncthreads();
  }
  int prev = (t == 0) ? 0 : part[t - 1];
#pragma unroll
  for (int i = 0; i < 16; ++i) {
    int idx = base + i;
    if (idx < N_NODES) { int st = prev + local[i]; start[idx] = st; cur[idx] = st; }
  }
  if (t == 0) start[N_NODES] = N_EDGES;
}

__global__ void k_fill(const int* __restrict__ esrc, const int* __restrict__ edst,
                       int* __restrict__ cur, int2* __restrict__ sd) {
  int e = blockIdx.x * 256 + threadIdx.x;
  int d = edst[e];
  int slot = atomicAdd(&cur[d], 1);
  sd[slot] = make_int2(esrc[e], d);
}

// ================= edge1 body (weights via W1/W2 ptrs; small mats RAW) =================
__device__ __forceinline__ void edge1_body(
    int slot, const float* __restrict__ pos, const float* __restrict__ x,
    const float* W1, const float* W2,
    const float* WQS, const float* WQV, const float* WSS, const float* WVV,
    const int2* __restrict__ sd, float* __restrict__ simb) {
  int2 e = sd[slot];
  int s = e.x, d = e.y;
  float h[16]; EdgeGeom g;
  edge_h(pos, s, d, W1, h, g);

  float qd[8], qvd[12];
  {
    float xd[40];
    load_row40(x + 40 * d, xd);
#pragma unroll
    for (int o = 0; o < 8; ++o) qd[o] = 0.f;
#pragma unroll
    for (int i = 0; i < 16; ++i)
#pragma unroll
      for (int o = 0; o < 8; ++o) qd[o] = fmaf(xd[i], WQS[8 * i + o], qd[o]);
#pragma unroll
    for (int k = 0; k < 12; ++k) qvd[k] = 0.f;
#pragma unroll
    for (int i = 0; i < 8; ++i)
#pragma unroll
      for (int o = 0; o < 4; ++o)
#pragma unroll
        for (int c = 0; c < 3; ++c)
          qvd[3 * o + c] = fmaf(xd[16 + 3 * i + c], WQV[4 * i + o], qvd[3 * o + c]);
  }

  float xr[40];
  load_row40(x + 40 * s, xr);
  const float* xs = xr;
  const float* xv = xr + 16;
  float B[8];
#pragma unroll
  for (int i = 0; i < 8; ++i)
    B[i] = fmaf(xv[3 * i], g.vhx, fmaf(xv[3 * i + 1], g.vhy, xv[3 * i + 2] * g.vhz));

  float ks[8];
#pragma unroll
  for (int o = 0; o < 8; ++o) {
    float acc = 0.f;
#pragma unroll
    for (int i = 0; i < 16; ++i) acc = fmaf(xs[i], dot16(h, W2 + ((i * 8 + o) << 4)), acc);
#pragma unroll
    for (int i = 0; i < 8; ++i)  acc = fmaf(B[i], dot16(h, W2 + ((128 + i * 8 + o) << 4)), acc);
    ks[o] = acc;
  }
  float kv[12];
#pragma unroll
  for (int o = 0; o < 4; ++o) {
    float s1 = 0.f;
#pragma unroll
    for (int i = 0; i < 16; ++i) s1 = fmaf(xs[i], dot16(h, W2 + ((192 + i * 4 + o) << 4)), s1);
    float s2x = 0.f, s2y = 0.f, s2z = 0.f;
#pragma unroll
    for (int i = 0; i < 8; ++i) {
      float w = dot16(h, W2 + ((256 + i * 4 + o) << 4));
      s2x = fmaf(xv[3 * i], w, s2x);
      s2y = fmaf(xv[3 * i + 1], w, s2y);
      s2z = fmaf(xv[3 * i + 2], w, s2z);
    }
    kv[3 * o]     = fmaf(g.y1x, s1, s2x);
    kv[3 * o + 1] = fmaf(g.y1y, s1, s2y);
    kv[3 * o + 2] = fmaf(g.y1z, s1, s2z);
  }

  float ss = 0.f;
#pragma unroll
  for (int jj = 0; jj < 8; ++jj) {
    float t = 0.f;
#pragma unroll
    for (int i = 0; i < 8; ++i) t = fmaf(qd[i], WSS[8 * i + jj], t);
    ss = fmaf(t, ks[jj], ss);
  }
  float sv = 0.f;
#pragma unroll
  for (int jj = 0; jj < 4; ++jj)
#pragma unroll
    for (int c = 0; c < 3; ++c) {
      float t = 0.f;
#pragma unroll
      for (int i = 0; i < 4; ++i) t = fmaf(qvd[3 * i + c], WVV[4 * i + jj], t);
      sv = fmaf(t, kv[3 * jj + c], sv);
    }
  simb[slot] = fmaf(C_SS, ss, C_SV * sv);
}

// ================= pass 1: dual-transport (even waves: LDS, odd waves: s_load) =================
// LDS (floats): [0,512) W1K scaled | [512,5120) W2K^T scaled | [5120,5248) WQS raw
//               [5248,5280) WQV raw | [5280,5344) WSS raw | [5344,5360) WVV raw
__global__ void __launch_bounds__(256) k_edge1(
    const float* __restrict__ pos, const float* __restrict__ x,
    const float* __restrict__ Wq_s, const float* __restrict__ Wq_v,
    const float* __restrict__ Wk1, const float* __restrict__ Wk2,
    const float* __restrict__ Wss, const float* __restrict__ Wvv,
    const float* __restrict__ WKg,
    const int2* __restrict__ sd, float* __restrict__ simb) {
  __shared__ float L[5360];
  for (int i = threadIdx.x; i < 5360; i += 256) {
    float v;
    if (i < 512) v = Wk1[i] * 0.17677669529663687f;
    else if (i < 5120) {
      int j = i - 512; int col = j >> 4, t = j & 15;
      v = Wk2[t * 288 + col] * 0.051031036307982884f;
    }
    else if (i < 5248) v = Wq_s[i - 5120];
    else if (i < 5280) v = Wq_v[i - 5248];
    else if (i < 5344) v = Wss[i - 5280];
    else               v = Wvv[i - 5344];
    L[i] = v;
  }
  __syncthreads();

  int slot = blockIdx.x * 256 + threadIdx.x;
  if ((threadIdx.x >> 6) & 1)
    edge1_body(slot, pos, x, WKg, WKg + 512, Wq_s, Wq_v, Wss, Wvv, sd, simb);
  else
    edge1_body(slot, pos, x, L, L + 512, L + 5120, L + 5248, L + 5280, L + 5344, sd, simb);
}

// ================= exact per-dst softmax: simb <- exp(sim - max)/Z =================
__global__ void k_norm(const int* __restrict__ start, float* __restrict__ simb) {
  int n = blockIdx.x * 256 + threadIdx.x;
  if (n >= N_NODES) return;
  int a = start[n], b = start[n + 1];
  if (a == b) return;
  float m = -3.4e38f;
  for (int j = a; j < b; ++j) m = fmaxf(m, simb[j]);
  float Z = 0.f;
  for (int j = a; j < b; ++j) { float t = __expf(simb[j] - m); simb[j] = t; Z += t; }
  float inv = 1.f / Z;
  for (int j = a; j < b; ++j) simb[j] *= inv;
}

// ================= edge2 body (1 edge/lane; weights via W1/W2 ptrs) =================
__device__ __forceinline__ void edge2_body(
    int slot, int lane, const float* __restrict__ pos, const float* __restrict__ x,
    const float* W1, const float* W2,
    const int2* __restrict__ sd, const float* __restrict__ ab, float* __restrict__ out) {
  int2 e = sd[slot];
  int s = e.x, d = e.y;

  bool same[6];
#pragma unroll
  for (int k = 0; k < 6; ++k) {
    int dd = __shfl_down(d, 1 << k, 64);
    same[k] = ((lane + (1 << k)) < 64) && (dd == d);
  }
  int dprev = __shfl_up(d, 1, 64);
  bool head = (lane == 0) || (dprev != d);

  float h[16]; EdgeGeom g;
  edge_h(pos, s, d, W1, h, g);
  float xr[40];
  load_row40(x + 40 * s, xr);
  const float* xs = xr;
  const float* xv = xr + 16;
  float B[8];
#pragma unroll
  for (int i = 0; i < 8; ++i)
    B[i] = fmaf(xv[3 * i], g.vhx, fmaf(xv[3 * i + 1], g.vhy, xv[3 * i + 2] * g.vhz));

  float a = ab[slot];
  float* op = out + 40 * d;

#pragma unroll
  for (int o = 0; o < 16; ++o) {
    float acc = 0.f;
#pragma unroll
    for (int i = 0; i < 16; ++i) acc = fmaf(xs[i], dot16(h, W2 + ((i * 16 + o) << 4)), acc);
#pragma unroll
    for (int i = 0; i < 8; ++i)  acc = fmaf(B[i], dot16(h, W2 + ((256 + i * 16 + o) << 4)), acc);
    float v = a * acc;
#pragma unroll
    for (int k = 0; k < 6; ++k) {
      float ov = __shfl_down(v, 1 << k, 64);
      v += same[k] ? ov : 0.f;
    }
    if (head) atomicAdd(op + o, v);
  }
#pragma unroll
  for (int o = 0; o < 8; ++o) {
    float s1 = 0.f;
#pragma unroll
    for (int i = 0; i < 16; ++i) s1 = fmaf(xs[i], dot16(h, W2 + ((384 + i * 8 + o) << 4)), s1);
    float s2x = 0.f, s2y = 0.f, s2z = 0.f;
#pragma unroll
    for (int i = 0; i < 8; ++i) {
      float w = dot16(h, W2 + ((512 + i * 8 + o) << 4));
      s2x = fmaf(xv[3 * i], w, s2x);
      s2y = fmaf(xv[3 * i + 1], w, s2y);
      s2z = fmaf(xv[3 * i + 2], w, s2z);
    }
    float vc[3];
    vc[0] = a * fmaf(g.y1x, s1, s2x);
    vc[1] = a * fmaf(g.y1y, s1, s2y);
    vc[2] = a * fmaf(g.y1z, s1, s2z);
#pragma unroll
    for (int c = 0; c < 3; ++c) {
      float v = vc[c];
#pragma unroll
      for (int k = 0; k < 6; ++k) {
        float ov = __shfl_down(v, 1 << k, 64);
        v += same[k] ? ov : 0.f;
      }
      if (head) atomicAdd(op + 16 + 3 * o + c, v);
    }
  }
}

// ================= pass 2: dual-transport (even waves: LDS, odd waves: s_load) =================
__global__ void __launch_bounds__(256) k_edge2(
    const float* __restrict__ pos, const float* __restrict__ x,
    const float* __restrict__ Wv1, const float* __restrict__ Wv2,
    const float* __restrict__ WVg,
    const int2* __restrict__ sd, const float* __restrict__ ab, float* __restrict__ out) {
  __shared__ float L[9728];
  for (int i = threadIdx.x; i < 9728; i += 256) {
    float v;
    if (i < 512) v = Wv1[i] * 0.17677669529663687f;
    else {
      int j = i - 512; int col = j >> 4, t = j & 15;
      v = Wv2[t * 576 + col] * 0.051031036307982884f;
    }
    L[i] = v;
  }
  __syncthreads();

  int slot = blockIdx.x * 256 + threadIdx.x;
  int lane = threadIdx.x & 63;
  if ((threadIdx.x >> 6) & 1)
    edge2_body(slot, lane, pos, x, WVg, WVg + 512, sd, ab, out);
  else
    edge2_body(slot, lane, pos, x, L, L + 512, sd, ab, out);
}

extern "C" void kernel_launch(void* const* d_in, const int* in_sizes, int n_in,
                              void* d_out, int out_size, void* d_ws, size_t ws_size,
                              hipStream_t stream) {
  (void)in_sizes; (void)n_in; (void)out_size; (void)ws_size;
  const float* pos  = (const float*)d_in[0];
  const float* x    = (const float*)d_in[1];
  const float* Wq_s = (const float*)d_in[2];
  const float* Wq_v = (const float*)d_in[3];
  const float* Wk1  = (const float*)d_in[4];
  const float* Wk2  = (const float*)d_in[5];
  const float* Wv1  = (const float*)d_in[6];
  const float* Wv2  = (const float*)d_in[7];
  const float* Wss  = (const float*)d_in[8];
  const float* Wvv  = (const float*)d_in[9];
  const int* esrc = (const int*)d_in[10];
  const int* edst = (const int*)d_in[11];
  int*   wsi  = (int*)d_ws;
  float* wsf  = (float*)d_ws;
  float* out  = (float*)d_out;

  int2*  sd    = (int2*)(wsi + OFF_SD);
  float* simb  = wsf + OFF_SIMB;
  int*   cnt   = wsi + OFF_CNT;
  int*   start = wsi + OFF_START;
  int*   cur   = wsi + OFF_CUR;
  float* WK    = wsf + OFF_WK;
  float* WV    = wsf + OFF_WV;

  hipMemsetAsync(cnt, 0, (size_t)N_NODES * sizeof(int), stream);
  hipMemsetAsync(out, 0, (size_t)(N_NODES * 40) * sizeof(float), stream);
  k_prep<<<40, 256, 0, stream>>>(Wk1, Wk2, Wv1, Wv2, WK, WV);
  k_hist<<<1000, 256, 0, stream>>>(edst, cnt);
  k_scan<<<1, 1024, 0, stream>>>(cnt, start, cur);
  k_fill<<<1000, 256, 0, stream>>>(esrc, edst, cur, sd);
  k_edge1<<<1000, 256, 0, stream>>>(pos, x, Wq_s, Wq_v, Wk1, Wk2, Wss, Wvv, WK, sd, simb);
  k_norm<<<63, 256, 0, stream>>>(start, simb);
  k_edge2<<<1000, 256, 0, stream>>>(pos, x, Wv1, Wv2, WV, sd, simb, out);
}

// Round 11
// 258.437 us; speedup vs baseline: 2.1497x; 2.1497x over previous
//
#include <hip/hip_runtime.h>
#include <hip/hip_bf16.h>

#define N_NODES 16000
#define N_EDGES 256000

// ---- workspace layout (4-byte units) — total 816001 * 4B = 3.26 MB (r9-validated) ----
#define OFF_SD     0          // int2  256000  (src,dst) per CSR slot, sorted by dst
#define OFF_SIMB   512000     // float 256000  raw sim -> normalized a (in place)
#define OFF_CNT    768000     // int   16000   per-dst degree
#define OFF_START  784000     // int   16001   CSR row offsets
#define OFF_CUR    800001     // int   16000   fill cursors

typedef _Float16 f16x2 __attribute__((ext_vector_type(2)));

__device__ __forceinline__ float fdot2f(f16x2 a, f16x2 b, float c) {
#if __has_builtin(__builtin_amdgcn_fdot2)
  return __builtin_amdgcn_fdot2(a, b, c, false);   // v_dot2_f32_f16, fp32 accumulate
#else
  return fmaf((float)a.x, (float)b.x, fmaf((float)a.y, (float)b.y, c));
#endif
}

__device__ __forceinline__ unsigned packh2(float a, float b) {
  union { unsigned u; f16x2 p; } v;
  v.p.x = (_Float16)a; v.p.y = (_Float16)b;
  return v.u;
}

// dot of h (8 packed f16 pairs) with a 16-f16 LDS column (8 dwords, 16B-aligned => 2x ds_read_b128)
__device__ __forceinline__ float dot16h(const f16x2* hp, const unsigned* w) {
  union { uint4 u; f16x2 p[4]; } a, b;
  a.u = *(const uint4*)(w);
  b.u = *(const uint4*)(w + 4);
  float r = 0.f;
  r = fdot2f(hp[0], a.p[0], r);
  r = fdot2f(hp[1], a.p[1], r);
  r = fdot2f(hp[2], a.p[2], r);
  r = fdot2f(hp[3], a.p[3], r);
  r = fdot2f(hp[4], b.p[0], r);
  r = fdot2f(hp[5], b.p[1], r);
  r = fdot2f(hp[6], b.p[2], r);
  r = fdot2f(hp[7], b.p[3], r);
  return r;
}

// load a 40-float row (rows are 160B = 16B-aligned) via 10 x float4
__device__ __forceinline__ void load_row40(const float* __restrict__ p, float* xr) {
  const float4* rp = reinterpret_cast<const float4*>(p);
#pragma unroll
  for (int q = 0; q < 10; ++q) {
    float4 f = rp[q];
    xr[4 * q + 0] = f.x; xr[4 * q + 1] = f.y; xr[4 * q + 2] = f.z; xr[4 * q + 3] = f.w;
  }
}

struct EdgeGeom { float vhx, vhy, vhz, y1x, y1y, y1z; };

// geometry + radial basis + h = silu(rad @ W1n), output packed as 8 f16 pairs.
// W1 (LDS, packed): [bp*16 + t] = half2(W1[2bp][t], W1[2bp+1][t]) * 1/sqrt(32)
__device__ __forceinline__ void edge_h_pk(const float* __restrict__ pos, int s, int d,
                                          const unsigned* W1, f16x2* hp, EdgeGeom& g) {
  float vx = pos[3 * d + 0] - pos[3 * s + 0];
  float vy = pos[3 * d + 1] - pos[3 * s + 1];
  float vz = pos[3 * d + 2] - pos[3 * s + 2];
  float dist = sqrtf(fmaf(vx, vx, fmaf(vy, vy, vz * vz)));
  float dsafe = fmaxf(dist, 1e-6f);
  float rinv = 1.0f / dsafe;
  g.vhx = vx * rinv; g.vhy = vy * rinv; g.vhz = vz * rinv;
  g.y1x = 1.7320508075688772f * g.vhx;
  g.y1y = 1.7320508075688772f * g.vhy;
  g.y1z = 1.7320508075688772f * g.vhz;
  float pre[16];
#pragma unroll
  for (int t = 0; t < 16; ++t) pre[t] = 0.f;
  float sx, cx;
  sincosf(1.2566370614359172f * dsafe, &sx, &cx);   // pi/R_CUT * dsafe
  cx = fminf(1.f, fmaxf(-1.f, cx));
  float twoc = 2.f * cx;
  float sprev = 0.f, scur = sx;
  float rscale = (dist < 2.5f) ? (5.059644256269407f * rinv) : 0.f;  // sqrt(2/2.5)*sqrt(32)
#pragma unroll
  for (int bp = 0; bp < 16; ++bp) {
    float r0 = rscale * scur;
    float sn = fmaf(twoc, scur, -sprev); sprev = scur; scur = sn;
    float r1 = rscale * scur;
    sn = fmaf(twoc, scur, -sprev); sprev = scur; scur = sn;
    union { unsigned u; f16x2 p; } rp; rp.p.x = (_Float16)r0; rp.p.y = (_Float16)r1;
    union { uint4 u[4]; f16x2 p[16]; } w;
    w.u[0] = *(const uint4*)(W1 + bp * 16);
    w.u[1] = *(const uint4*)(W1 + bp * 16 + 4);
    w.u[2] = *(const uint4*)(W1 + bp * 16 + 8);
    w.u[3] = *(const uint4*)(W1 + bp * 16 + 12);
#pragma unroll
    for (int t = 0; t < 16; ++t) pre[t] = fdot2f(rp.p, w.p[t], pre[t]);
  }
#pragma unroll
  for (int tp = 0; tp < 8; ++tp) {
    float h0 = pre[2 * tp]     / (1.f + __expf(-pre[2 * tp]));      // silu (fp32)
    float h1 = pre[2 * tp + 1] / (1.f + __expf(-pre[2 * tp + 1]));
    hp[tp].x = (_Float16)h0; hp[tp].y = (_Float16)h1;
  }
}

// ================= CSR build =================
__global__ void k_hist(const int* __restrict__ edst, int* __restrict__ cnt) {
  int e = blockIdx.x * 256 + threadIdx.x;
  atomicAdd(&cnt[edst[e]], 1);
}

__global__ void __launch_bounds__(1024) k_scan(const int* __restrict__ cnt,
                                               int* __restrict__ start, int* __restrict__ cur) {
  __shared__ int part[1024];
  int t = threadIdx.x;
  int base = t * 16;
  int local[16];
  int sum = 0;
#pragma unroll
  for (int i = 0; i < 16; ++i) {
    int idx = base + i;
    int c = (idx < N_NODES) ? cnt[idx] : 0;
    local[i] = sum; sum += c;
  }
  part[t] = sum;
  __syncthreads();
  for (int off = 1; off < 1024; off <<= 1) {
    int v = (t >= off) ? part[t - off] : 0;
    __syncthreads();
    part[t] += v;
    __syncthreads();
  }
  int prev = (t == 0) ? 0 : part[t - 1];
#pragma unroll
  for (int i = 0; i < 16; ++i) {
    int idx = base + i;
    if (idx < N_NODES) { int st = prev + local[i]; start[idx] = st; cur[idx] = st; }
  }
  if (t == 0) start[N_NODES] = N_EDGES;
}

__global__ void k_fill(const int* __restrict__ esrc, const int* __restrict__ edst,
                       int* __restrict__ cur, int2* __restrict__ sd) {
  int e = blockIdx.x * 256 + threadIdx.x;
  int d = edst[e];
  int slot = atomicAdd(&cur[d], 1);
  sd[slot] = make_int2(esrc[e], d);
}

// ================= pass 1: q + k TP (f16-packed weights) + raw sim =================
// Lw (uint): [0,256) W1K packed | [256,2560) W2K^T packed [col*8+tp], scaled 1/sqrt16/sqrt24
// Ls (float): [0,128) WQS*0.25 | [128,160) WQV/sqrt8 | [160,224) WSS/sqrt80 | [224,240) WVV/(sqrt80*sqrt3)
__global__ void __launch_bounds__(256) k_edge1(
    const float* __restrict__ pos, const float* __restrict__ x,
    const float* __restrict__ Wq_s, const float* __restrict__ Wq_v,
    const float* __restrict__ Wk1, const float* __restrict__ Wk2,
    const float* __restrict__ Wss, const float* __restrict__ Wvv,
    const int2* __restrict__ sd, float* __restrict__ simb) {
  __shared__ __align__(16) unsigned Lw[2560];
  __shared__ float Ls[240];
  for (int i = threadIdx.x; i < 2560; i += 256) {
    unsigned v;
    if (i < 256) {
      int bp = i >> 4, t = i & 15;
      v = packh2(Wk1[(2 * bp) * 16 + t] * 0.17677669529663687f,
                 Wk1[(2 * bp + 1) * 16 + t] * 0.17677669529663687f);
    } else {
      int j = i - 256; int col = j >> 3, tp = j & 7;
      v = packh2(Wk2[(2 * tp) * 288 + col] * 0.051031036307982884f,
                 Wk2[(2 * tp + 1) * 288 + col] * 0.051031036307982884f);
    }
    Lw[i] = v;
  }
  for (int i = threadIdx.x; i < 240; i += 256) {
    float v;
    if (i < 128)      v = Wq_s[i] * 0.25f;
    else if (i < 160) v = Wq_v[i - 128] * 0.3535533905932738f;
    else if (i < 224) v = Wss[i - 160] * 0.11180339887498948f;
    else              v = Wvv[i - 224] * 0.06454972243679028f;
    Ls[i] = v;
  }
  __syncthreads();

  int slot = blockIdx.x * 256 + threadIdx.x;
  int2 e = sd[slot];
  int s = e.x, d = e.y;
  f16x2 hp[8]; EdgeGeom g;
  edge_h_pk(pos, s, d, Lw, hp, g);

  float qd[8], qvd[12];
  {
    float xd[40];
    load_row40(x + 40 * d, xd);   // consecutive slots share d -> L1-resident
#pragma unroll
    for (int o = 0; o < 8; ++o) qd[o] = 0.f;
#pragma unroll
    for (int i = 0; i < 16; ++i)
#pragma unroll
      for (int o = 0; o < 8; ++o) qd[o] = fmaf(xd[i], Ls[8 * i + o], qd[o]);
#pragma unroll
    for (int k = 0; k < 12; ++k) qvd[k] = 0.f;
#pragma unroll
    for (int i = 0; i < 8; ++i)
#pragma unroll
      for (int o = 0; o < 4; ++o)
#pragma unroll
        for (int c = 0; c < 3; ++c)
          qvd[3 * o + c] = fmaf(xd[16 + 3 * i + c], Ls[128 + 4 * i + o], qvd[3 * o + c]);
  }

  float xr[40];
  load_row40(x + 40 * s, xr);
  const float* xs = xr;
  const float* xv = xr + 16;
  float B[8];
#pragma unroll
  for (int i = 0; i < 8; ++i)
    B[i] = fmaf(xv[3 * i], g.vhx, fmaf(xv[3 * i + 1], g.vhy, xv[3 * i + 2] * g.vhz));

  const unsigned* W2 = Lw + 256;
  float ks[8];
#pragma unroll
  for (int o = 0; o < 8; ++o) {
    float acc = 0.f;
#pragma unroll
    for (int i = 0; i < 16; ++i) acc = fmaf(xs[i], dot16h(hp, W2 + ((i * 8 + o) << 3)), acc);
#pragma unroll
    for (int i = 0; i < 8; ++i)  acc = fmaf(B[i], dot16h(hp, W2 + ((128 + i * 8 + o) << 3)), acc);
    ks[o] = acc;
  }
  float kv[12];
#pragma unroll
  for (int o = 0; o < 4; ++o) {
    float s1 = 0.f;
#pragma unroll
    for (int i = 0; i < 16; ++i) s1 = fmaf(xs[i], dot16h(hp, W2 + ((192 + i * 4 + o) << 3)), s1);
    float s2x = 0.f, s2y = 0.f, s2z = 0.f;
#pragma unroll
    for (int i = 0; i < 8; ++i) {
      float w = dot16h(hp, W2 + ((256 + i * 4 + o) << 3));
      s2x = fmaf(xv[3 * i], w, s2x);
      s2y = fmaf(xv[3 * i + 1], w, s2y);
      s2z = fmaf(xv[3 * i + 2], w, s2z);
    }
    kv[3 * o]     = fmaf(g.y1x, s1, s2x);
    kv[3 * o + 1] = fmaf(g.y1y, s1, s2y);
    kv[3 * o + 2] = fmaf(g.y1z, s1, s2z);
  }

  float sim = 0.f;
#pragma unroll
  for (int jj = 0; jj < 8; ++jj) {
    float t = 0.f;
#pragma unroll
    for (int i = 0; i < 8; ++i) t = fmaf(qd[i], Ls[160 + 8 * i + jj], t);
    sim = fmaf(t, ks[jj], sim);
  }
#pragma unroll
  for (int jj = 0; jj < 4; ++jj)
#pragma unroll
    for (int c = 0; c < 3; ++c) {
      float t = 0.f;
#pragma unroll
      for (int i = 0; i < 4; ++i) t = fmaf(qvd[3 * i + c], Ls[224 + 4 * i + jj], t);
      sim = fmaf(t, kv[3 * jj + c], sim);
    }
  simb[slot] = sim;
}

// ================= exact per-dst softmax: simb <- exp(sim - max)/Z =================
__global__ void k_norm(const int* __restrict__ start, float* __restrict__ simb) {
  int n = blockIdx.x * 256 + threadIdx.x;
  if (n >= N_NODES) return;
  int a = start[n], b = start[n + 1];
  if (a == b) return;
  float m = -3.4e38f;
  for (int j = a; j < b; ++j) m = fmaxf(m, simb[j]);
  float Z = 0.f;
  for (int j = a; j < b; ++j) { float t = __expf(simb[j] - m); simb[j] = t; Z += t; }
  float inv = 1.f / Z;
  for (int j = a; j < b; ++j) simb[j] *= inv;
}

// ================= pass 2: v TP (f16-packed weights) + wave-segmented scatter =================
// Lw (uint): [0,256) W1V packed | [256,4864) W2V^T packed [col*8+tp], scaled
__global__ void __launch_bounds__(256) k_edge2(
    const float* __restrict__ pos, const float* __restrict__ x,
    const float* __restrict__ Wv1, const float* __restrict__ Wv2,
    const int2* __restrict__ sd, const float* __restrict__ ab, float* __restrict__ out) {
  __shared__ __align__(16) unsigned Lw[4864];
  for (int i = threadIdx.x; i < 4864; i += 256) {
    unsigned v;
    if (i < 256) {
      int bp = i >> 4, t = i & 15;
      v = packh2(Wv1[(2 * bp) * 16 + t] * 0.17677669529663687f,
                 Wv1[(2 * bp + 1) * 16 + t] * 0.17677669529663687f);
    } else {
      int j = i - 256; int col = j >> 3, tp = j & 7;
      v = packh2(Wv2[(2 * tp) * 576 + col] * 0.051031036307982884f,
                 Wv2[(2 * tp + 1) * 576 + col] * 0.051031036307982884f);
    }
    Lw[i] = v;
  }
  __syncthreads();

  int slot = blockIdx.x * 256 + threadIdx.x;   // CSR slot (sorted by dst)
  int lane = threadIdx.x & 63;
  int2 e = sd[slot];
  int s = e.x, d = e.y;

  bool same[6];
#pragma unroll
  for (int k = 0; k < 6; ++k) {
    int dd = __shfl_down(d, 1 << k, 64);
    same[k] = ((lane + (1 << k)) < 64) && (dd == d);
  }
  int dprev = __shfl_up(d, 1, 64);
  bool head = (lane == 0) || (dprev != d);

  f16x2 hp[8]; EdgeGeom g;
  edge_h_pk(pos, s, d, Lw, hp, g);
  float xr[40];
  load_row40(x + 40 * s, xr);
  const float* xs = xr;
  const float* xv = xr + 16;
  float B[8];
#pragma unroll
  for (int i = 0; i < 8; ++i)
    B[i] = fmaf(xv[3 * i], g.vhx, fmaf(xv[3 * i + 1], g.vhy, xv[3 * i + 2] * g.vhz));

  float a = ab[slot];
  const unsigned* W2 = Lw + 256;
  float* op = out + 40 * d;

#pragma unroll
  for (int o = 0; o < 16; ++o) {
    float acc = 0.f;
#pragma unroll
    for (int i = 0; i < 16; ++i) acc = fmaf(xs[i], dot16h(hp, W2 + ((i * 16 + o) << 3)), acc);
#pragma unroll
    for (int i = 0; i < 8; ++i)  acc = fmaf(B[i], dot16h(hp, W2 + ((256 + i * 16 + o) << 3)), acc);
    float v = a * acc;
#pragma unroll
    for (int k = 0; k < 6; ++k) {
      float ov = __shfl_down(v, 1 << k, 64);
      v += same[k] ? ov : 0.f;
    }
    if (head) atomicAdd(op + o, v);
  }
#pragma unroll
  for (int o = 0; o < 8; ++o) {
    float s1 = 0.f;
#pragma unroll
    for (int i = 0; i < 16; ++i) s1 = fmaf(xs[i], dot16h(hp, W2 + ((384 + i * 8 + o) << 3)), s1);
    float s2x = 0.f, s2y = 0.f, s2z = 0.f;
#pragma unroll
    for (int i = 0; i < 8; ++i) {
      float w = dot16h(hp, W2 + ((512 + i * 8 + o) << 3));
      s2x = fmaf(xv[3 * i], w, s2x);
      s2y = fmaf(xv[3 * i + 1], w, s2y);
      s2z = fmaf(xv[3 * i + 2], w, s2z);
    }
    float vc[3];
    vc[0] = a * fmaf(g.y1x, s1, s2x);
    vc[1] = a * fmaf(g.y1y, s1, s2y);
    vc[2] = a * fmaf(g.y1z, s1, s2z);
#pragma unroll
    for (int c = 0; c < 3; ++c) {
      float v = vc[c];
#pragma unroll
      for (int k = 0; k < 6; ++k) {
        float ov = __shfl_down(v, 1 << k, 64);
        v += same[k] ? ov : 0.f;
      }
      if (head) atomicAdd(op + 16 + 3 * o + c, v);
    }
  }
}

extern "C" void kernel_launch(void* const* d_in, const int* in_sizes, int n_in,
                              void* d_out, int out_size, void* d_ws, size_t ws_size,
                              hipStream_t stream) {
  (void)in_sizes; (void)n_in; (void)out_size; (void)ws_size;
  const float* pos  = (const float*)d_in[0];
  const float* x    = (const float*)d_in[1];
  const float* Wq_s = (const float*)d_in[2];
  const float* Wq_v = (const float*)d_in[3];
  const float* Wk1  = (const float*)d_in[4];
  const float* Wk2  = (const float*)d_in[5];
  const float* Wv1  = (const float*)d_in[6];
  const float* Wv2  = (const float*)d_in[7];
  const float* Wss  = (const float*)d_in[8];
  const float* Wvv  = (const float*)d_in[9];
  const int* esrc = (const int*)d_in[10];
  const int* edst = (const int*)d_in[11];
  int*   wsi  = (int*)d_ws;
  float* wsf  = (float*)d_ws;
  float* out  = (float*)d_out;

  int2*  sd    = (int2*)(wsi + OFF_SD);
  float* simb  = wsf + OFF_SIMB;
  int*   cnt   = wsi + OFF_CNT;
  int*   start = wsi + OFF_START;
  int*   cur   = wsi + OFF_CUR;

  hipMemsetAsync(cnt, 0, (size_t)N_NODES * sizeof(int), stream);
  hipMemsetAsync(out, 0, (size_t)(N_NODES * 40) * sizeof(float), stream);
  k_hist<<<1000, 256, 0, stream>>>(edst, cnt);
  k_scan<<<1, 1024, 0, stream>>>(cnt, start, cur);
  k_fill<<<1000, 256, 0, stream>>>(esrc, edst, cur, sd);
  k_edge1<<<1000, 256, 0, stream>>>(pos, x, Wq_s, Wq_v, Wk1, Wk2, Wss, Wvv, sd, simb);
  k_norm<<<63, 256, 0, stream>>>(start, simb);
  k_edge2<<<1000, 256, 0, stream>>>(pos, x, Wv1, Wv2, sd, simb, out);
}